// Round 1
// baseline (66.640 us; speedup 1.0000x reference)
//
#include <hip/hip_runtime.h>
#include <hip/hip_bf16.h>
#include <stdint.h>

// Locally-connected layer: X[128,32,32,64] f32, filters[900,576,64] f32
// -> out[128,30,30,64] f32.  900 per-location GEMMs: M=128(batch) x N=64(fout) x K=576.
// One workgroup per location l. bf16 MFMA 16x16x32, fp32 accumulate.

typedef __attribute__((ext_vector_type(4))) float  f32x4;
typedef __attribute__((ext_vector_type(8))) short  short8;
typedef __attribute__((ext_vector_type(4))) short  short4v;

#define BOFF 16384  // byte offset of B tile in LDS (A tile = 128 rows * 128B)

// XOR swizzle: 16B chunk index within a 128B row xor'd with row bits.
// Verified: A/B fragment b128 reads and staging writes are all uniformly
// spread (8 lanes per 16B slot for b128 = the 1KB/wave floor).
__device__ __forceinline__ uint32_t swz_addr(uint32_t row, uint32_t inrow) {
    uint32_t chunk = inrow >> 4;
    uint32_t rem   = inrow & 15u;
    return row * 128u + (((chunk ^ row ^ (row >> 3)) & 7u) << 4) + rem;
}

__device__ __forceinline__ short f2bf(float x) {
    __hip_bfloat16 h = __float2bfloat16(x);
    short r;
    __builtin_memcpy(&r, &h, 2);
    return r;
}

__global__ __launch_bounds__(256)
void lc_mfma_kernel(const float* __restrict__ X,
                    const float* __restrict__ Fl,
                    float* __restrict__ Out) {
    __shared__ __align__(16) unsigned char lds[24576];
    // lds[0      .. 16384): A tile, 128 rows (batch) x 64 bf16 (k of this step), swizzled
    // lds[16384  .. 24576): B tile,  64 rows (fout)  x 64 bf16 (k of this step), swizzled

    const int l  = blockIdx.x;        // output location 0..899
    const int oi = l / 30;
    const int oj = l % 30;
    const int tid  = threadIdx.x;
    const int lane = tid & 63;
    const int wave = tid >> 6;

    f32x4 acc[2][4];
#pragma unroll
    for (int m = 0; m < 2; ++m)
#pragma unroll
        for (int n = 0; n < 4; ++n)
            acc[m][n] = f32x4{0.f, 0.f, 0.f, 0.f};

    // A staging: 2 iters x (row = it*64 + tid>>2, quarter aq = tid&3 -> fin aq*16..+15)
    const int ar = tid >> 2;
    const int aq = tid & 3;
    // B staging: thread owns a 4(k) x 4(f) block: f = fq*4+i, k = k0..k0+3
    const int fq = tid & 15;
    const int k0 = (tid >> 4) * 4;

    const float* Fb = Fl + (size_t)l * (576 * 64);

#pragma unroll 1
    for (int s = 0; s < 9; ++s) {
        const int di = s / 3, dj = s % 3;
        const int h = oi + di, w = oj + dj;

        __syncthreads();  // previous step's LDS reads done before overwrite

        // ---- stage A: X[row, h, w, fin] -> Alds[row][fin] (bf16, swizzled) ----
#pragma unroll
        for (int it = 0; it < 2; ++it) {
            const int row = it * 64 + ar;
            const float* src = X + (((size_t)row * 32 + h) * 32 + w) * 64 + aq * 16;
            const float4 v0 = ((const float4*)src)[0];
            const float4 v1 = ((const float4*)src)[1];
            const float4 v2 = ((const float4*)src)[2];
            const float4 v3 = ((const float4*)src)[3];
            short8 p0, p1;
            p0[0]=f2bf(v0.x); p0[1]=f2bf(v0.y); p0[2]=f2bf(v0.z); p0[3]=f2bf(v0.w);
            p0[4]=f2bf(v1.x); p0[5]=f2bf(v1.y); p0[6]=f2bf(v1.z); p0[7]=f2bf(v1.w);
            p1[0]=f2bf(v2.x); p1[1]=f2bf(v2.y); p1[2]=f2bf(v2.z); p1[3]=f2bf(v2.w);
            p1[4]=f2bf(v3.x); p1[5]=f2bf(v3.y); p1[6]=f2bf(v3.z); p1[7]=f2bf(v3.w);
            *(short8*)&lds[swz_addr(row, aq * 32 + 0 )] = p0;
            *(short8*)&lds[swz_addr(row, aq * 32 + 16)] = p1;
        }

        // ---- stage B: filters[l, s*64 + k, f] -> Blds[f][k] (bf16, transposed, swizzled) ----
        {
            const float* src = Fb + (size_t)s * 4096 + (size_t)k0 * 64 + fq * 4;
            const float4 r0 = ((const float4*)(src +   0))[0];
            const float4 r1 = ((const float4*)(src +  64))[0];
            const float4 r2 = ((const float4*)(src + 128))[0];
            const float4 r3 = ((const float4*)(src + 192))[0];
            const short4v c0 = { f2bf(r0.x), f2bf(r1.x), f2bf(r2.x), f2bf(r3.x) };
            const short4v c1 = { f2bf(r0.y), f2bf(r1.y), f2bf(r2.y), f2bf(r3.y) };
            const short4v c2 = { f2bf(r0.z), f2bf(r1.z), f2bf(r2.z), f2bf(r3.z) };
            const short4v c3 = { f2bf(r0.w), f2bf(r1.w), f2bf(r2.w), f2bf(r3.w) };
            *(short4v*)&lds[BOFF + swz_addr(fq * 4 + 0, k0 * 2)] = c0;
            *(short4v*)&lds[BOFF + swz_addr(fq * 4 + 1, k0 * 2)] = c1;
            *(short4v*)&lds[BOFF + swz_addr(fq * 4 + 2, k0 * 2)] = c2;
            *(short4v*)&lds[BOFF + swz_addr(fq * 4 + 3, k0 * 2)] = c3;
        }

        __syncthreads();

        // ---- compute: 16 MFMA per wave per step ----
        const int mb   = wave * 32;
        const int rsel = lane & 15;
        const int ksel = (lane >> 4) * 16;   // byte offset of this lane-group's 8 bf16
#pragma unroll
        for (int kk = 0; kk < 2; ++kk) {
            const uint32_t inrow = (uint32_t)(kk * 64 + ksel);
            const short8 a0 = *(const short8*)&lds[swz_addr(mb + rsel,      inrow)];
            const short8 a1 = *(const short8*)&lds[swz_addr(mb + 16 + rsel, inrow)];
            const short8 b0 = *(const short8*)&lds[BOFF + swz_addr(     rsel, inrow)];
            const short8 b1 = *(const short8*)&lds[BOFF + swz_addr(16 + rsel, inrow)];
            const short8 b2 = *(const short8*)&lds[BOFF + swz_addr(32 + rsel, inrow)];
            const short8 b3 = *(const short8*)&lds[BOFF + swz_addr(48 + rsel, inrow)];
            acc[0][0] = __builtin_amdgcn_mfma_f32_16x16x32_bf16(a0, b0, acc[0][0], 0, 0, 0);
            acc[0][1] = __builtin_amdgcn_mfma_f32_16x16x32_bf16(a0, b1, acc[0][1], 0, 0, 0);
            acc[0][2] = __builtin_amdgcn_mfma_f32_16x16x32_bf16(a0, b2, acc[0][2], 0, 0, 0);
            acc[0][3] = __builtin_amdgcn_mfma_f32_16x16x32_bf16(a0, b3, acc[0][3], 0, 0, 0);
            acc[1][0] = __builtin_amdgcn_mfma_f32_16x16x32_bf16(a1, b0, acc[1][0], 0, 0, 0);
            acc[1][1] = __builtin_amdgcn_mfma_f32_16x16x32_bf16(a1, b1, acc[1][1], 0, 0, 0);
            acc[1][2] = __builtin_amdgcn_mfma_f32_16x16x32_bf16(a1, b2, acc[1][2], 0, 0, 0);
            acc[1][3] = __builtin_amdgcn_mfma_f32_16x16x32_bf16(a1, b3, acc[1][3], 0, 0, 0);
        }
    }

    // ---- epilogue: D layout col=lane&15, row=(lane>>4)*4+reg (m89-verified) ----
    const int col = lane & 15;
    const int rb  = (lane >> 4) * 4;
#pragma unroll
    for (int m = 0; m < 2; ++m)
#pragma unroll
        for (int n = 0; n < 4; ++n)
#pragma unroll
            for (int i = 0; i < 4; ++i) {
                const int row = wave * 32 + m * 16 + rb + i;  // batch index
                const int f   = n * 16 + col;                 // fout index
                Out[((size_t)row * 900 + l) * 64 + f] = acc[m][n][i];
            }
}

extern "C" void kernel_launch(void* const* d_in, const int* in_sizes, int n_in,
                              void* d_out, int out_size, void* d_ws, size_t ws_size,
                              hipStream_t stream) {
    const float* X  = (const float*)d_in[0];   // [128,32,32,64]
    const float* Fl = (const float*)d_in[1];   // [900,576,64]
    float* Out = (float*)d_out;                // [128,30,30,64]
    lc_mfma_kernel<<<dim3(900), dim3(256), 0, stream>>>(X, Fl, Out);
}

// Round 2
// 40.525 us; speedup vs baseline: 1.6444x; 1.6444x over previous
//
#include <hip/hip_runtime.h>
#include <hip/hip_bf16.h>
#include <stdint.h>

// Locally-connected layer: X[128,32,32,64] f32, filters[900,576,64] f32
// -> out[128,30,30,64] f32.  900 per-location GEMMs: M=128 x N=64 x K=576.
// One WG per location. bf16 MFMA 16x16x32, fp32 accumulate.
// R2: LDS double-buffer + register prefetch (issue loads for step s+1 before
// compute of step s) + bijective XCD-chunked swizzle for X L2 locality.

typedef __attribute__((ext_vector_type(4))) float  f32x4;
typedef __attribute__((ext_vector_type(8))) short  short8;
typedef __attribute__((ext_vector_type(4))) short  short4v;

#define BOFF 16384  // byte offset of B tile inside one LDS buffer

// XOR swizzle on 16B chunks within a 128B row (verified uniform for all
// staging writes + fragment b128 reads).
__device__ __forceinline__ uint32_t swz_addr(uint32_t row, uint32_t inrow) {
    uint32_t chunk = inrow >> 4;
    uint32_t rem   = inrow & 15u;
    return row * 128u + (((chunk ^ row ^ (row >> 3)) & 7u) << 4) + rem;
}

__device__ __forceinline__ short f2bf(float x) {
    __hip_bfloat16 h = __float2bfloat16(x);
    short r;
    __builtin_memcpy(&r, &h, 2);
    return r;
}

__global__ __launch_bounds__(256)
void lc_mfma_kernel(const float* __restrict__ X,
                    const float* __restrict__ Fl,
                    float* __restrict__ Out) {
    __shared__ __align__(16) unsigned char lds[2][24576];
    // each buffer: [0,16384) A tile 128rows x 64 bf16 (swizzled)
    //              [16384,24576) B tile 64rows(fout) x 64 bf16 (swizzled)

    // Bijective XCD-chunked swizzle: 8 XCDs, nwg=900 -> q=112, r=4.
    // XCD i gets a contiguous band of locations (X-row reuse in its L2).
    const int orig = blockIdx.x;
    const int xcd  = orig & 7;
    const int idx  = orig >> 3;
    const int l    = (xcd < 4 ? xcd * 113 : 452 + (xcd - 4) * 112) + idx;

    const int oi = l / 30;
    const int oj = l % 30;
    const int tid  = threadIdx.x;
    const int lane = tid & 63;
    const int wave = tid >> 6;

    f32x4 acc[2][4];
#pragma unroll
    for (int m = 0; m < 2; ++m)
#pragma unroll
        for (int n = 0; n < 4; ++n)
            acc[m][n] = f32x4{0.f, 0.f, 0.f, 0.f};

    // A staging: thread covers rows {ar, 64+ar}, fin quarter aq*16..+15
    const int ar = tid >> 2;
    const int aq = tid & 3;
    // B staging: thread covers f = fq*4..+3 (transposed), k = k0..k0+3
    const int fq = tid & 15;
    const int k0 = (tid >> 4) * 4;

    const float* Fb = Fl + (size_t)l * (576 * 64);

    float4 av[8];  // prefetched A regs (2 rows x 4 float4)
    float4 bv[4];  // prefetched B regs (4 k-rows x 1 float4)

#define ISSUE_LOADS(S)                                                          \
    do {                                                                        \
        const int di_ = (S) / 3, dj_ = (S) % 3;                                 \
        const int h_ = oi + di_, w_ = oj + dj_;                                 \
        const float* a0_ = X + (((size_t)ar * 32 + h_) * 32 + w_) * 64 + aq*16; \
        const float* a1_ = a0_ + (size_t)64 * 32 * 32 * 64;                     \
        av[0] = ((const float4*)a0_)[0]; av[1] = ((const float4*)a0_)[1];       \
        av[2] = ((const float4*)a0_)[2]; av[3] = ((const float4*)a0_)[3];       \
        av[4] = ((const float4*)a1_)[0]; av[5] = ((const float4*)a1_)[1];       \
        av[6] = ((const float4*)a1_)[2]; av[7] = ((const float4*)a1_)[3];       \
        const float* b_ = Fb + (size_t)(S) * 4096 + (size_t)k0 * 64 + fq * 4;   \
        bv[0] = *(const float4*)(b_);       bv[1] = *(const float4*)(b_ + 64);  \
        bv[2] = *(const float4*)(b_ + 128); bv[3] = *(const float4*)(b_ + 192); \
    } while (0)

#define WRITE_LDS(BUF)                                                          \
    do {                                                                        \
        unsigned char* L_ = lds[BUF];                                           \
        _Pragma("unroll")                                                       \
        for (int it = 0; it < 2; ++it) {                                        \
            const float4 v0 = av[it*4+0], v1 = av[it*4+1];                      \
            const float4 v2 = av[it*4+2], v3 = av[it*4+3];                      \
            short8 p0, p1;                                                      \
            p0[0]=f2bf(v0.x); p0[1]=f2bf(v0.y); p0[2]=f2bf(v0.z); p0[3]=f2bf(v0.w); \
            p0[4]=f2bf(v1.x); p0[5]=f2bf(v1.y); p0[6]=f2bf(v1.z); p0[7]=f2bf(v1.w); \
            p1[0]=f2bf(v2.x); p1[1]=f2bf(v2.y); p1[2]=f2bf(v2.z); p1[3]=f2bf(v2.w); \
            p1[4]=f2bf(v3.x); p1[5]=f2bf(v3.y); p1[6]=f2bf(v3.z); p1[7]=f2bf(v3.w); \
            *(short8*)&L_[swz_addr(it*64 + ar, aq*32 + 0 )] = p0;               \
            *(short8*)&L_[swz_addr(it*64 + ar, aq*32 + 16)] = p1;               \
        }                                                                       \
        const short4v c0 = { f2bf(bv[0].x), f2bf(bv[1].x), f2bf(bv[2].x), f2bf(bv[3].x) }; \
        const short4v c1 = { f2bf(bv[0].y), f2bf(bv[1].y), f2bf(bv[2].y), f2bf(bv[3].y) }; \
        const short4v c2 = { f2bf(bv[0].z), f2bf(bv[1].z), f2bf(bv[2].z), f2bf(bv[3].z) }; \
        const short4v c3 = { f2bf(bv[0].w), f2bf(bv[1].w), f2bf(bv[2].w), f2bf(bv[3].w) }; \
        *(short4v*)&L_[BOFF + swz_addr(fq*4 + 0, k0*2)] = c0;                   \
        *(short4v*)&L_[BOFF + swz_addr(fq*4 + 1, k0*2)] = c1;                   \
        *(short4v*)&L_[BOFF + swz_addr(fq*4 + 2, k0*2)] = c2;                   \
        *(short4v*)&L_[BOFF + swz_addr(fq*4 + 3, k0*2)] = c3;                   \
    } while (0)

    // prologue: stage step 0 into buffer 0
    ISSUE_LOADS(0);
    WRITE_LDS(0);

    const int mb   = wave * 32;
    const int rsel = lane & 15;
    const int ksel = (lane >> 4) * 16;

#pragma unroll 1
    for (int s = 0; s < 9; ++s) {
        // issue next step's global loads BEFORE barrier+compute (latency hides
        // under barrier + ds_read + MFMA; vmcnt wait lands at WRITE_LDS below)
        if (s < 8) ISSUE_LOADS(s + 1);

        __syncthreads();  // lds[s&1] writes (prev iter / prologue) visible

        const unsigned char* L = lds[s & 1];
#pragma unroll
        for (int kk = 0; kk < 2; ++kk) {
            const uint32_t inrow = (uint32_t)(kk * 64 + ksel);
            const short8 a0 = *(const short8*)&L[swz_addr(mb + rsel,      inrow)];
            const short8 a1 = *(const short8*)&L[swz_addr(mb + 16 + rsel, inrow)];
            const short8 b0 = *(const short8*)&L[BOFF + swz_addr(     rsel, inrow)];
            const short8 b1 = *(const short8*)&L[BOFF + swz_addr(16 + rsel, inrow)];
            const short8 b2 = *(const short8*)&L[BOFF + swz_addr(32 + rsel, inrow)];
            const short8 b3 = *(const short8*)&L[BOFF + swz_addr(48 + rsel, inrow)];
            acc[0][0] = __builtin_amdgcn_mfma_f32_16x16x32_bf16(a0, b0, acc[0][0], 0, 0, 0);
            acc[0][1] = __builtin_amdgcn_mfma_f32_16x16x32_bf16(a0, b1, acc[0][1], 0, 0, 0);
            acc[0][2] = __builtin_amdgcn_mfma_f32_16x16x32_bf16(a0, b2, acc[0][2], 0, 0, 0);
            acc[0][3] = __builtin_amdgcn_mfma_f32_16x16x32_bf16(a0, b3, acc[0][3], 0, 0, 0);
            acc[1][0] = __builtin_amdgcn_mfma_f32_16x16x32_bf16(a1, b0, acc[1][0], 0, 0, 0);
            acc[1][1] = __builtin_amdgcn_mfma_f32_16x16x32_bf16(a1, b1, acc[1][1], 0, 0, 0);
            acc[1][2] = __builtin_amdgcn_mfma_f32_16x16x32_bf16(a1, b2, acc[1][2], 0, 0, 0);
            acc[1][3] = __builtin_amdgcn_mfma_f32_16x16x32_bf16(a1, b3, acc[1][3], 0, 0, 0);
        }

        // write next step into the other buffer; safe (that buffer's readers
        // all passed the barrier above). No second barrier needed.
        if (s < 8) WRITE_LDS((s + 1) & 1);
    }

    // epilogue: D layout col=lane&15, row=(lane>>4)*4+reg (m89-verified)
    const int col = lane & 15;
    const int rb  = (lane >> 4) * 4;
#pragma unroll
    for (int m = 0; m < 2; ++m)
#pragma unroll
        for (int n = 0; n < 4; ++n)
#pragma unroll
            for (int i = 0; i < 4; ++i) {
                const int row = wave * 32 + m * 16 + rb + i;
                const int f   = n * 16 + col;
                Out[((size_t)row * 900 + l) * 64 + f] = acc[m][n][i];
            }
}

extern "C" void kernel_launch(void* const* d_in, const int* in_sizes, int n_in,
                              void* d_out, int out_size, void* d_ws, size_t ws_size,
                              hipStream_t stream) {
    const float* X  = (const float*)d_in[0];   // [128,32,32,64]
    const float* Fl = (const float*)d_in[1];   // [900,576,64]
    float* Out = (float*)d_out;                // [128,30,30,64]
    lc_mfma_kernel<<<dim3(900), dim3(256), 0, stream>>>(X, Fl, Out);
}